// Round 8
// baseline (263.103 us; speedup 1.0000x reference)
//
#include <hip/hip_runtime.h>
#include <hip/hip_cooperative_groups.h>
#include <hip/hip_bf16.h>

namespace cg = cooperative_groups;

typedef __bf16 bf16_t;
typedef __bf16 bf16x4 __attribute__((ext_vector_type(4)));
typedef __bf16 bf16x8 __attribute__((ext_vector_type(8)));
typedef float f32x4 __attribute__((ext_vector_type(4)));

#define M_TOT 8192
#define N_TOT 512
#define K_TOT 2048
#define E_TOT 512
#define NSEG_HALF 8       // 8 segments of BK=128 per k-slice (K=2048 split x2)

__device__ __forceinline__ bf16x8 zero8() {
    bf16x8 v;
#pragma unroll
    for (int i = 0; i < 8; ++i) v[i] = (bf16_t)0.0f;
    return v;
}

// ---------------------------------------------------------------------------
// shared device helpers (proven R5 versions, unchanged)
// ---------------------------------------------------------------------------
// B segment: 64n x 128k bf16 = 16KB, as two 64x64 k-tiles. LDS byte layout is
// LINEAR in s (byte = s*16, s=0..1023): tile=s>>9, n=(s>>3)&63, seg=s&7.
// XOR swizzle (slot seg holds global k-chunk g=seg^(n&7)) applied on the
// GLOBAL source address, LDS dest linear -> global_load_lds legal.
__device__ __forceinline__ void stage_B(const bf16_t* __restrict__ W2t,
                                        bf16_t* dst_buf, int n_base, int k0,
                                        int wl, int l) {
#pragma unroll
    for (int j = 0; j < 4; ++j) {
        int s    = wl * 64 + l + j * 256;  // this lane's 16B slot (0..1023)
        int tile = s >> 9;
        int n    = (s >> 3) & 63;
        int g    = (s & 7) ^ (n & 7);
        const bf16_t* src = W2t + (size_t)(n_base + n) * K_TOT
                            + k0 + tile * 64 + g * 8;
        bf16_t* ldst = dst_buf + (size_t)(wl * 64 + j * 256) * 8;
        __builtin_amdgcn_global_load_lds(
            (const __attribute__((address_space(1))) unsigned int*)src,
            (__attribute__((address_space(3))) unsigned int*)ldst,
            16, 0, 0);
    }
}

__device__ __forceinline__ void load_wf(const bf16_t* __restrict__ W1p, int k0,
                                        int l15, int lq, bf16x8 wf[4]) {
#pragma unroll
    for (int i = 0; i < 4; ++i) wf[i] = zero8();
    if (lq < 2) {
        const int base = (k0 >> 5) * 2;
#pragma unroll
        for (int i = 0; i < 4; ++i)
            wf[i] = *(const bf16x8*)(W1p + (size_t)((base + i) * 16 + l15) * 16 + lq * 8);
    }
}

// one 64-k tile: B frags from LDS, h in registers (layout-matched MFMA), mains.
// wave tile 32m x 64n. MFMA order per acc register unchanged -> bit-identical.
__device__ __forceinline__ void compute_tile(const bf16_t* Bb, const bf16x8 wf[4],
                                             const bf16x8 zfrag[2],
                                             int l15, int lq,
                                             f32x4 acc[2][4]) {
    bf16x8 bfr[2][4];
#pragma unroll
    for (int c = 0; c < 2; ++c)
#pragma unroll
        for (int nt = 0; nt < 4; ++nt) {
            int r = nt * 16 + l15;
            int s = (c * 4 + lq) ^ (r & 7);
            bfr[c][nt] = *(const bf16x8*)(Bb + r * 64 + s * 8);
        }

    bf16x8 af[2][2];
#pragma unroll
    for (int mt = 0; mt < 2; ++mt)
#pragma unroll
        for (int c = 0; c < 2; ++c) {
            f32x4 h0 = (f32x4){0.f, 0.f, 0.f, 0.f};
            f32x4 h1 = (f32x4){0.f, 0.f, 0.f, 0.f};
            h0 = __builtin_amdgcn_mfma_f32_16x16x32_bf16(wf[c * 2 + 0], zfrag[mt], h0, 0, 0, 0);
            h1 = __builtin_amdgcn_mfma_f32_16x16x32_bf16(wf[c * 2 + 1], zfrag[mt], h1, 0, 0, 0);
            bf16x8 a;
#pragma unroll
            for (int r = 0; r < 4; ++r) {
                a[r]     = (bf16_t)fmaxf(h0[r], 0.f);
                a[r + 4] = (bf16_t)fmaxf(h1[r], 0.f);
            }
            af[mt][c] = a;
        }

#pragma unroll
    for (int c = 0; c < 2; ++c)
#pragma unroll
        for (int mt = 0; mt < 2; ++mt)
#pragma unroll
            for (int nt = 0; nt < 4; ++nt)
                acc[mt][nt] = __builtin_amdgcn_mfma_f32_16x16x32_bf16(
                    af[mt][c], bfr[c][nt], acc[mt][nt], 0, 0, 0);
}

// GEMM phase body (verbatim R5 structure), shared by fused + fallback kernels.
// Block 128m x 64n, 8 waves = 4 m-slots (32m) x 2 K-SLICES; split-K combine
// through LDS; double-buffered BK=128 staging via global_load_lds.
__device__ __forceinline__ void gemm_body(int b_n, int b_m, int t,
                                          const bf16_t* __restrict__ zb,
                                          const bf16_t* __restrict__ W1p,
                                          const bf16_t* __restrict__ W2t,
                                          const float* __restrict__ b2,
                                          float* __restrict__ out,
                                          bf16_t (*Blds)[2][2 * 64 * 64]) {
    const int w  = t >> 6, l = t & 63;
    const int ks = w >> 2;                // k-slice 0/1
    const int wl = w & 3;                 // m-slot of 32 rows
    const int m_base = b_m * 128;
    const int n_base = b_n * 64;
    const int l15 = l & 15, lq = l >> 4;
    const int k_base = ks * 1024;

    bf16x8 zfrag[2];
#pragma unroll
    for (int mt = 0; mt < 2; ++mt) {
        zfrag[mt] = zero8();
        if (lq < 2)
            zfrag[mt] = *(const bf16x8*)(zb + (size_t)(m_base + wl * 32 + mt * 16 + l15) * 16 + lq * 8);
    }

    f32x4 acc[2][4];
#pragma unroll
    for (int mt = 0; mt < 2; ++mt)
#pragma unroll
        for (int nt = 0; nt < 4; ++nt)
            acc[mt][nt] = (f32x4){0.f, 0.f, 0.f, 0.f};

    stage_B(W2t, Blds[ks][0], n_base, k_base, wl, l);

    for (int s = 0; s < NSEG_HALF; ++s) {
        const int cur = s & 1;
        __syncthreads();                   // vmcnt(0) drain + publish buf[cur]
        if (s + 1 < NSEG_HALF)
            stage_B(W2t, Blds[ks][1 - cur], n_base, k_base + (s + 1) * 128, wl, l);

#pragma unroll
        for (int tt = 0; tt < 2; ++tt) {
            bf16x8 wf[4];
            load_wf(W1p, k_base + s * 128 + tt * 64, l15, lq, wf);
            compute_tile(Blds[ks][cur] + tt * 4096, wf, zfrag, l15, lq, acc);
        }
    }

    // ---- split-K combine through LDS (reuse Blds as f32 scratch) ----
    __syncthreads();
    float* F = (float*)&Blds[0][0][0];
    if (ks == 1) {
#pragma unroll
        for (int mt = 0; mt < 2; ++mt)
#pragma unroll
            for (int nt = 0; nt < 4; ++nt) {
                int idx = ((wl * 2 + mt) * 4 + nt) * 64 + l;
                *(f32x4*)(F + (size_t)idx * 4) = acc[mt][nt];
            }
    }
    __syncthreads();
    if (ks == 0) {
#pragma unroll
        for (int nt = 0; nt < 4; ++nt) {
            int col = n_base + nt * 16 + l15;
            float bias = b2[col];
#pragma unroll
            for (int mt = 0; mt < 2; ++mt) {
                int idx = ((wl * 2 + mt) * 4 + nt) * 64 + l;
                f32x4 part = *(const f32x4*)(F + (size_t)idx * 4);
#pragma unroll
                for (int r = 0; r < 4; ++r) {
                    int row = m_base + wl * 32 + mt * 16 + lq * 4 + r;
                    out[(size_t)row * N_TOT + col] = acc[mt][nt][r] + part[r] + bias;
                }
            }
        }
    }
}

// ---------------------------------------------------------------------------
// FUSED cooperative kernel: prep (phase A) + grid.sync + GEMM (phase B).
// Grid 512 blocks x 512 thr = exactly 2 blocks/CU x 256 CU co-resident
// (LDS 64KB/block), the sanctioned hipLaunchCooperativeKernel case.
// Phase A work split: blocks [0,256) transpose one 64x64 W2 tile each
// (512 threads, 2 iters); blocks [256,272) zb (512 rows each);
// blocks [272,276) W1p (512 rows each); rest idle.
// Removes the prep kernel launch + inter-kernel gap (~8-11 us).
// ---------------------------------------------------------------------------
__global__ __launch_bounds__(512, 4)
void ffq_fused_kernel(const float* __restrict__ x,
                      const float* __restrict__ theta,
                      const float* __restrict__ W1,
                      const float* __restrict__ b1,
                      const float* __restrict__ W2,
                      const float* __restrict__ b2,
                      bf16_t* __restrict__ W2t,
                      bf16_t* __restrict__ zb,
                      bf16_t* __restrict__ W1p,
                      float* __restrict__ out)
{
    __shared__ bf16_t Blds[2][2][2 * 64 * 64];   // 64 KB; aliased by prep's T

    const int b = blockIdx.x;                    // 0..511
    const int t = threadIdx.x;                   // 0..511

    // ---------------- phase A: prep ----------------
    if (b < 256) {
        // W2[k][n] -> W2t[n][k] transpose of one 64x64 tile, bf16 cvt.
        bf16_t (*T)[66] = reinterpret_cast<bf16_t (*)[66]>(&Blds[0][0][0]);
        const int k0 = (b >> 3) * 64;
        const int n0 = (b & 7) * 64;
        const int kl = t >> 4;                   // 0..31
        const int n4 = t & 15;
#pragma unroll
        for (int i = 0; i < 2; ++i) {
            int k = kl + i * 32;
            float4 v = *(const float4*)(W2 + (size_t)(k0 + k) * N_TOT + n0 + n4 * 4);
            T[n4 * 4 + 0][k] = (bf16_t)v.x;
            T[n4 * 4 + 1][k] = (bf16_t)v.y;
            T[n4 * 4 + 2][k] = (bf16_t)v.z;
            T[n4 * 4 + 3][k] = (bf16_t)v.w;
        }
        __syncthreads();
        const int nl = t >> 4;
        const int k4 = t & 15;
#pragma unroll
        for (int i = 0; i < 2; ++i) {
            int n = nl + i * 32;
            bf16x4 v;
            v[0] = T[n][k4 * 4 + 0];
            v[1] = T[n][k4 * 4 + 1];
            v[2] = T[n][k4 * 4 + 2];
            v[3] = T[n][k4 * 4 + 3];
            *(bf16x4*)(W2t + (size_t)(n0 + n) * K_TOT + k0 + k4 * 4) = v;
        }
    } else if (b < 272) {
        // zb[m][0..8)=cos(theta[q])*cos(x[m,q]); zb[m][8]=1 (bias lane)
        const int m = (b - 256) * 512 + t;       // 0..8191
        float4 x0 = *(const float4*)(x + (size_t)m * E_TOT);
        float4 x1 = *(const float4*)(x + (size_t)m * E_TOT + 4);
        float xs[8] = {x0.x, x0.y, x0.z, x0.w, x1.x, x1.y, x1.z, x1.w};
        bf16x8 lo;
#pragma unroll
        for (int q = 0; q < 8; ++q)
            lo[q] = (bf16_t)(__builtin_cosf(theta[q]) * __builtin_cosf(xs[q]));
        bf16x8 hi = zero8();
        hi[0] = (bf16_t)1.0f;
        *(bf16x8*)(zb + (size_t)m * 16)     = lo;
        *(bf16x8*)(zb + (size_t)m * 16 + 8) = hi;
    } else if (b < 276) {
        // W1p: permuted W1 rows + bias (h-MFMA C-out == main-MFMA A-frag)
        const int d  = (b - 272) * 512 + t;      // 0..2047
        const int c  = d >> 5;
        const int dd = d & 31;
        const int p  = dd >> 4;
        const int rr = dd & 15;
        const int f  = c * 32 + ((rr >> 2) << 3) + (p << 2) + (rr & 3);
        bf16x8 lo;
#pragma unroll
        for (int q = 0; q < 8; ++q)
            lo[q] = (bf16_t)W1[(size_t)q * K_TOT + f];
        bf16x8 hi = zero8();
        hi[0] = (bf16_t)b1[f];
        *(bf16x8*)(W1p + (size_t)d * 16)     = lo;
        *(bf16x8*)(W1p + (size_t)d * 16 + 8) = hi;
    }

    __threadfence();                // publish prep writes device-wide
    cg::this_grid().sync();         // grid-wide barrier (cooperative launch)

    // ---------------- phase B: GEMM (verbatim R5 body) ----------------
    gemm_body(b & 7, b >> 3, t, zb, W1p, W2t, b2, out, Blds);
}

// ---------------------------------------------------------------------------
// Fallback path (proven R5 kernels) if cooperative launch is rejected.
// ---------------------------------------------------------------------------
__global__ __launch_bounds__(256)
void prep4_kernel(const float* __restrict__ x,
                  const float* __restrict__ theta,
                  const float* __restrict__ W1,
                  const float* __restrict__ b1,
                  const float* __restrict__ W2,
                  bf16_t* __restrict__ W2t,
                  bf16_t* __restrict__ zb,
                  bf16_t* __restrict__ W1p)
{
    const int b = blockIdx.x;
    if (b < 256) {
        __shared__ bf16_t T[64][66];
        const int k0 = (b >> 3) * 64;
        const int n0 = (b & 7) * 64;
        const int kl = threadIdx.x >> 4;
        const int n4 = threadIdx.x & 15;
#pragma unroll
        for (int i = 0; i < 4; ++i) {
            int k = kl + i * 16;
            float4 v = *(const float4*)(W2 + (size_t)(k0 + k) * N_TOT + n0 + n4 * 4);
            T[n4 * 4 + 0][k] = (bf16_t)v.x;
            T[n4 * 4 + 1][k] = (bf16_t)v.y;
            T[n4 * 4 + 2][k] = (bf16_t)v.z;
            T[n4 * 4 + 3][k] = (bf16_t)v.w;
        }
        __syncthreads();
        const int nl = threadIdx.x >> 4;
        const int k4 = threadIdx.x & 15;
#pragma unroll
        for (int i = 0; i < 4; ++i) {
            int n = nl + i * 16;
            bf16x4 v;
            v[0] = T[n][k4 * 4 + 0];
            v[1] = T[n][k4 * 4 + 1];
            v[2] = T[n][k4 * 4 + 2];
            v[3] = T[n][k4 * 4 + 3];
            *(bf16x4*)(W2t + (size_t)(n0 + n) * K_TOT + k0 + k4 * 4) = v;
        }
    } else if (b < 288) {
        const int m = (b - 256) * 256 + threadIdx.x;
        float4 x0 = *(const float4*)(x + (size_t)m * E_TOT);
        float4 x1 = *(const float4*)(x + (size_t)m * E_TOT + 4);
        float xs[8] = {x0.x, x0.y, x0.z, x0.w, x1.x, x1.y, x1.z, x1.w};
        bf16x8 lo;
#pragma unroll
        for (int q = 0; q < 8; ++q)
            lo[q] = (bf16_t)(__builtin_cosf(theta[q]) * __builtin_cosf(xs[q]));
        bf16x8 hi = zero8();
        hi[0] = (bf16_t)1.0f;
        *(bf16x8*)(zb + (size_t)m * 16)     = lo;
        *(bf16x8*)(zb + (size_t)m * 16 + 8) = hi;
    } else {
        const int d  = (b - 288) * 256 + threadIdx.x;
        const int c  = d >> 5;
        const int dd = d & 31;
        const int p  = dd >> 4;
        const int rr = dd & 15;
        const int f  = c * 32 + ((rr >> 2) << 3) + (p << 2) + (rr & 3);
        bf16x8 lo;
#pragma unroll
        for (int q = 0; q < 8; ++q)
            lo[q] = (bf16_t)W1[(size_t)q * K_TOT + f];
        bf16x8 hi = zero8();
        hi[0] = (bf16_t)b1[f];
        *(bf16x8*)(W1p + (size_t)d * 16)     = lo;
        *(bf16x8*)(W1p + (size_t)d * 16 + 8) = hi;
    }
}

__global__ __launch_bounds__(512, 4)
void ffq_gemm_kernel(const bf16_t* __restrict__ zb,
                     const bf16_t* __restrict__ W1p,
                     const bf16_t* __restrict__ W2t,
                     const float* __restrict__ b2,
                     float* __restrict__ out)
{
    __shared__ bf16_t Blds[2][2][2 * 64 * 64];
    gemm_body(blockIdx.x, blockIdx.y, threadIdx.x, zb, W1p, W2t, b2, out, Blds);
}

extern "C" void kernel_launch(void* const* d_in, const int* in_sizes, int n_in,
                              void* d_out, int out_size, void* d_ws, size_t ws_size,
                              hipStream_t stream) {
    const float* x     = (const float*)d_in[0];
    const float* theta = (const float*)d_in[1];
    const float* W1    = (const float*)d_in[2];
    const float* b1    = (const float*)d_in[3];
    const float* W2    = (const float*)d_in[4];
    const float* b2    = (const float*)d_in[5];
    float* out = (float*)d_out;

    // ws: [0,2MB) W2t ; [2MB,2.25MB) zb[8192][16] ; then W1p[2048][16]
    const size_t W2T_BYTES = (size_t)N_TOT * K_TOT * sizeof(bf16_t);  // 2 MB
    const size_t ZB_BYTES  = (size_t)M_TOT * 16 * sizeof(bf16_t);     // 256 KB

    bf16_t* W2t = (bf16_t*)d_ws;
    bf16_t* zb  = (bf16_t*)((char*)d_ws + W2T_BYTES);
    bf16_t* W1p = (bf16_t*)((char*)d_ws + W2T_BYTES + ZB_BYTES);

    void* args[] = { (void*)&x, (void*)&theta, (void*)&W1, (void*)&b1,
                     (void*)&W2, (void*)&b2, (void*)&W2t, (void*)&zb,
                     (void*)&W1p, (void*)&out };
    hipError_t err = hipLaunchCooperativeKernel(
        reinterpret_cast<void*>(ffq_fused_kernel),
        dim3(512), dim3(512), args, 0, stream);

    if (err != hipSuccess) {
        // proven two-kernel R5 path
        prep4_kernel<<<296, 256, 0, stream>>>(x, theta, W1, b1, W2, W2t, zb, W1p);
        dim3 grid(N_TOT / 64, M_TOT / 128);   // (8, 64) = 512 blocks, 2/CU
        ffq_gemm_kernel<<<grid, 512, 0, stream>>>(zb, W1p, W2t, b2, out);
    }
}

// Round 9
// 102.912 us; speedup vs baseline: 2.5566x; 2.5566x over previous
//
#include <hip/hip_runtime.h>
#include <hip/hip_bf16.h>

typedef __bf16 bf16_t;
typedef __bf16 bf16x4 __attribute__((ext_vector_type(4)));
typedef __bf16 bf16x8 __attribute__((ext_vector_type(8)));
typedef float f32x4 __attribute__((ext_vector_type(4)));

#define M_TOT 8192
#define N_TOT 512
#define K_TOT 2048
#define E_TOT 512
#define NSEG_HALF 16      // 16 segments of BK=64 per k-slice (K=2048 split x2)

__device__ __forceinline__ bf16x8 zero8() {
    bf16x8 v;
#pragma unroll
    for (int i = 0; i < 8; ++i) v[i] = (bf16_t)0.0f;
    return v;
}

// ---------------------------------------------------------------------------
// prep4 (unchanged; correctness-proven):
//  blocks [0,256):   LDS-tiled transpose W2[k][n] -> W2t[n][k] bf16
//  blocks [256,288): zb[m][0..8)=cos(theta[q])*cos(x[m,q]) (RX collapse:
//                    |a2|^2-|b2|^2 = cos(theta)*cos(x)); zb[m][8]=1; rest 0
//  blocks [288,296): W1p: permuted W1 rows + bias so h-MFMA C-output lands
//    exactly in main-MFMA A-fragment layout.
//    Row d=(c*2+p)*16+rr holds f = c*32+(rr>>2)*8+p*4+(rr&3).
// ---------------------------------------------------------------------------
__global__ __launch_bounds__(256)
void prep4_kernel(const float* __restrict__ x,
                  const float* __restrict__ theta,
                  const float* __restrict__ W1,
                  const float* __restrict__ b1,
                  const float* __restrict__ W2,
                  bf16_t* __restrict__ W2t,
                  bf16_t* __restrict__ zb,
                  bf16_t* __restrict__ W1p)
{
    const int b = blockIdx.x;
    if (b < 256) {
        __shared__ bf16_t T[64][66];
        const int k0 = (b >> 3) * 64;
        const int n0 = (b & 7) * 64;
        const int kl = threadIdx.x >> 4;
        const int n4 = threadIdx.x & 15;
#pragma unroll
        for (int i = 0; i < 4; ++i) {
            int k = kl + i * 16;
            float4 v = *(const float4*)(W2 + (size_t)(k0 + k) * N_TOT + n0 + n4 * 4);
            T[n4 * 4 + 0][k] = (bf16_t)v.x;
            T[n4 * 4 + 1][k] = (bf16_t)v.y;
            T[n4 * 4 + 2][k] = (bf16_t)v.z;
            T[n4 * 4 + 3][k] = (bf16_t)v.w;
        }
        __syncthreads();
        const int nl = threadIdx.x >> 4;
        const int k4 = threadIdx.x & 15;
#pragma unroll
        for (int i = 0; i < 4; ++i) {
            int n = nl + i * 16;
            bf16x4 v;
            v[0] = T[n][k4 * 4 + 0];
            v[1] = T[n][k4 * 4 + 1];
            v[2] = T[n][k4 * 4 + 2];
            v[3] = T[n][k4 * 4 + 3];
            *(bf16x4*)(W2t + (size_t)(n0 + n) * K_TOT + k0 + k4 * 4) = v;
        }
    } else if (b < 288) {
        const int m = (b - 256) * 256 + threadIdx.x;
        float4 x0 = *(const float4*)(x + (size_t)m * E_TOT);
        float4 x1 = *(const float4*)(x + (size_t)m * E_TOT + 4);
        float xs[8] = {x0.x, x0.y, x0.z, x0.w, x1.x, x1.y, x1.z, x1.w};
        bf16x8 lo;
#pragma unroll
        for (int q = 0; q < 8; ++q)
            lo[q] = (bf16_t)(__builtin_cosf(theta[q]) * __builtin_cosf(xs[q]));
        bf16x8 hi = zero8();
        hi[0] = (bf16_t)1.0f;                  // bias lane at k=8
        *(bf16x8*)(zb + (size_t)m * 16)     = lo;
        *(bf16x8*)(zb + (size_t)m * 16 + 8) = hi;
    } else {
        const int d  = (b - 288) * 256 + threadIdx.x;    // 0..2047
        const int c  = d >> 5;
        const int dd = d & 31;
        const int p  = dd >> 4;
        const int rr = dd & 15;
        const int f  = c * 32 + ((rr >> 2) << 3) + (p << 2) + (rr & 3);
        bf16x8 lo;
#pragma unroll
        for (int q = 0; q < 8; ++q)
            lo[q] = (bf16_t)W1[(size_t)q * K_TOT + f];
        bf16x8 hi = zero8();
        hi[0] = (bf16_t)b1[f];                 // bias at k=8
        *(bf16x8*)(W1p + (size_t)d * 16)     = lo;
        *(bf16x8*)(W1p + (size_t)d * 16 + 8) = hi;
    }
}

// ---------------------------------------------------------------------------
// helpers (256-thread block = 4 waves: 2 m-slots x 2 k-slices;
//          block tile 64m x 64n, per-slice segment BK=64)
// ---------------------------------------------------------------------------
// B segment: 64n x 64k bf16 = 8KB (one k-tile). LDS byte layout LINEAR in
// s (byte = s*16, s=0..511): n=(s>>3)&63, seg=s&7. XOR swizzle (slot seg
// holds global k-chunk g=seg^(n&7)) applied on the GLOBAL source address,
// LDS dest linear -> global_load_lds legal (wave-uniform base + lane*16);
// swizzled ds_read side unchanged. Staged by the slice's 128 threads
// (2 waves x 4 slots each).
__device__ __forceinline__ void stage_B(const bf16_t* __restrict__ W2t,
                                        bf16_t* dst_buf, int n_base, int k0,
                                        int wl, int l) {
#pragma unroll
    for (int j = 0; j < 4; ++j) {
        int s = wl * 64 + l + j * 128;     // this lane's 16B slot (0..511)
        int n = (s >> 3) & 63;
        int g = (s & 7) ^ (n & 7);
        const bf16_t* src = W2t + (size_t)(n_base + n) * K_TOT + k0 + g * 8;
        // wave-uniform LDS base for (wl,j); HW adds lane*16 -> byte s*16
        bf16_t* ldst = dst_buf + (size_t)(wl * 64 + j * 128) * 8;
        __builtin_amdgcn_global_load_lds(
            (const __attribute__((address_space(1))) unsigned int*)src,
            (__attribute__((address_space(3))) unsigned int*)ldst,
            16, 0, 0);
    }
}

// W1p frags for one 64-k tile (2 chunks x 2 perm-halves); lanes lq<2 real.
// k0 is the ABSOLUTE k offset (works for either k-slice).
__device__ __forceinline__ void load_wf(const bf16_t* __restrict__ W1p, int k0,
                                        int l15, int lq, bf16x8 wf[4]) {
#pragma unroll
    for (int i = 0; i < 4; ++i) wf[i] = zero8();
    if (lq < 2) {
        const int base = (k0 >> 5) * 2;
#pragma unroll
        for (int i = 0; i < 4; ++i)
            wf[i] = *(const bf16x8*)(W1p + (size_t)((base + i) * 16 + l15) * 16 + lq * 8);
    }
}

// one 64-k tile: B frags from LDS, h in registers (layout-matched MFMA), mains.
// wave tile 32m x 64n: each bfr feeds BOTH mt sub-tiles (low LDS bytes/FLOP).
// Per-acc k-chunk sequence identical to the proven R5 kernel (s x c order
// spans the same k ordering) -> bit-identical numerics.
__device__ __forceinline__ void compute_tile(const bf16_t* Bb, const bf16x8 wf[4],
                                             const bf16x8 zfrag[2],
                                             int l15, int lq,
                                             f32x4 acc[2][4]) {
    bf16x8 bfr[2][4];
#pragma unroll
    for (int c = 0; c < 2; ++c)
#pragma unroll
        for (int nt = 0; nt < 4; ++nt) {
            int r = nt * 16 + l15;
            int s = (c * 4 + lq) ^ (r & 7);
            bfr[c][nt] = *(const bf16x8*)(Bb + r * 64 + s * 8);
        }

    bf16x8 af[2][2];
#pragma unroll
    for (int mt = 0; mt < 2; ++mt)
#pragma unroll
        for (int c = 0; c < 2; ++c) {
            f32x4 h0 = (f32x4){0.f, 0.f, 0.f, 0.f};
            f32x4 h1 = (f32x4){0.f, 0.f, 0.f, 0.f};
            h0 = __builtin_amdgcn_mfma_f32_16x16x32_bf16(wf[c * 2 + 0], zfrag[mt], h0, 0, 0, 0);
            h1 = __builtin_amdgcn_mfma_f32_16x16x32_bf16(wf[c * 2 + 1], zfrag[mt], h1, 0, 0, 0);
            bf16x8 a;
#pragma unroll
            for (int r = 0; r < 4; ++r) {
                a[r]     = (bf16_t)fmaxf(h0[r], 0.f);
                a[r + 4] = (bf16_t)fmaxf(h1[r], 0.f);
            }
            af[mt][c] = a;
        }

#pragma unroll
    for (int c = 0; c < 2; ++c)
#pragma unroll
        for (int mt = 0; mt < 2; ++mt)
#pragma unroll
            for (int nt = 0; nt < 4; ++nt)
                acc[mt][nt] = __builtin_amdgcn_mfma_f32_16x16x32_bf16(
                    af[mt][c], bfr[c][nt], acc[mt][nt], 0, 0, 0);
}

// ---------------------------------------------------------------------------
// Fused GEMM: out = relu(z@W1+b1) @ W2 + b2
// Block 64m x 64n, 256 thr = 4 waves = 2 m-slots (32m each) x 2 K-SLICES.
// Split-K x2: slice ks handles k in [ks*1024,(ks+1)*1024), each with its own
// independent double-buffered BK=64 pipeline (LDS 2 slices x 2 bufs x 8KB =
// 32KB/block). Final combine through LDS (slice1 dumps f32 partials, slice0
// adds + bias + stores) -- deterministic, no atomics.
// Grid (8,128)=1024 blocks = 4 blocks/CU -> 16 waves/CU (4/SIMD) with FOUR
// independent barrier pipelines per CU (R5 had two): R5's cycle accounting
// showed ~9900 cyc/segment against ~500 cyc of issue work -- waves park at
// the per-segment vmcnt(0)+barrier in block-wide lockstep, and 2 blocks/CU
// under-fill the holes. Doubling independent pipelines is the one occupancy
// lever not yet tried at the 32m-wave shape (R2's 16 waves/CU won at 16m).
// B staging via global_load_lds width=16 (async direct-to-LDS).
// h entirely in registers via layout-matched h-MFMA (permuted W1p).
// ---------------------------------------------------------------------------
__global__ __launch_bounds__(256, 4)
void ffq_gemm_kernel(const bf16_t* __restrict__ zb,    // [8192][16]
                     const bf16_t* __restrict__ W1p,   // [2048][16] permuted
                     const bf16_t* __restrict__ W2t,   // [512][2048]
                     const float* __restrict__ b2,
                     float* __restrict__ out)          // [8192][512]
{
    __shared__ bf16_t Blds[2][2][64 * 64];   // [kslice][buf][one 64x64 tile]

    const int t  = threadIdx.x;           // 0..255
    const int w  = t >> 6, l = t & 63;
    const int ks = w >> 1;                // k-slice 0/1
    const int wl = w & 1;                 // m-slot of 32 rows
    const int m_base = blockIdx.y * 64;
    const int n_base = blockIdx.x * 64;
    const int l15 = l & 15, lq = l >> 4;
    const int k_base = ks * 1024;

    // persistent z^T B-frags for this wave's two 16-row m-tiles
    bf16x8 zfrag[2];
#pragma unroll
    for (int mt = 0; mt < 2; ++mt) {
        zfrag[mt] = zero8();
        if (lq < 2)
            zfrag[mt] = *(const bf16x8*)(zb + (size_t)(m_base + wl * 32 + mt * 16 + l15) * 16 + lq * 8);
    }

    f32x4 acc[2][4];
#pragma unroll
    for (int mt = 0; mt < 2; ++mt)
#pragma unroll
        for (int nt = 0; nt < 4; ++nt)
            acc[mt][nt] = (f32x4){0.f, 0.f, 0.f, 0.f};

    // prologue: this slice's segment 0 -> buf0 (async; first barrier drains)
    stage_B(W2t, Blds[ks][0], n_base, k_base, wl, l);

    for (int s = 0; s < NSEG_HALF; ++s) {
        const int cur = s & 1;
        __syncthreads();                   // vmcnt(0) drain + publish buf[cur]
        if (s + 1 < NSEG_HALF)
            stage_B(W2t, Blds[ks][1 - cur], n_base, k_base + (s + 1) * 64, wl, l);

        bf16x8 wf[4];
        load_wf(W1p, k_base + s * 64, l15, lq, wf);
        compute_tile(Blds[ks][cur], wf, zfrag, l15, lq, acc);
    }

    // ---- split-K combine through LDS (reuse Blds as f32 scratch) ----
    __syncthreads();                       // all LDS reads of B done
    float* F = (float*)&Blds[0][0][0];     // 16KB needed, 32KB available
    if (ks == 1) {
#pragma unroll
        for (int mt = 0; mt < 2; ++mt)
#pragma unroll
            for (int nt = 0; nt < 4; ++nt) {
                int idx = ((wl * 2 + mt) * 4 + nt) * 64 + l;   // lane-contig 16B
                *(f32x4*)(F + (size_t)idx * 4) = acc[mt][nt];
            }
    }
    __syncthreads();
    if (ks == 0) {
        // ---- epilogue: C/D layout col=lane&15, row=(lane>>4)*4+r ----
#pragma unroll
        for (int nt = 0; nt < 4; ++nt) {
            int col = n_base + nt * 16 + l15;
            float bias = b2[col];
#pragma unroll
            for (int mt = 0; mt < 2; ++mt) {
                int idx = ((wl * 2 + mt) * 4 + nt) * 64 + l;
                f32x4 part = *(const f32x4*)(F + (size_t)idx * 4);
#pragma unroll
                for (int r = 0; r < 4; ++r) {
                    int row = m_base + wl * 32 + mt * 16 + lq * 4 + r;
                    out[(size_t)row * N_TOT + col] = acc[mt][nt][r] + part[r] + bias;
                }
            }
        }
    }
}

extern "C" void kernel_launch(void* const* d_in, const int* in_sizes, int n_in,
                              void* d_out, int out_size, void* d_ws, size_t ws_size,
                              hipStream_t stream) {
    const float* x     = (const float*)d_in[0];
    const float* theta = (const float*)d_in[1];
    const float* W1    = (const float*)d_in[2];
    const float* b1    = (const float*)d_in[3];
    const float* W2    = (const float*)d_in[4];
    const float* b2    = (const float*)d_in[5];
    float* out = (float*)d_out;

    // ws: [0,2MB) W2t ; [2MB,2.25MB) zb[8192][16] ; then W1p[2048][16]
    const size_t W2T_BYTES = (size_t)N_TOT * K_TOT * sizeof(bf16_t);  // 2 MB
    const size_t ZB_BYTES  = (size_t)M_TOT * 16 * sizeof(bf16_t);     // 256 KB

    bf16_t* W2t = (bf16_t*)d_ws;
    bf16_t* zb  = (bf16_t*)((char*)d_ws + W2T_BYTES);
    bf16_t* W1p = (bf16_t*)((char*)d_ws + W2T_BYTES + ZB_BYTES);

    prep4_kernel<<<296, 256, 0, stream>>>(x, theta, W1, b1, W2, W2t, zb, W1p);

    dim3 grid(N_TOT / 64, M_TOT / 64);    // (8, 128) = 1024 blocks, 4/CU
    ffq_gemm_kernel<<<grid, 256, 0, stream>>>(zb, W1p, W2t, b2, out);
}